// Round 6
// baseline (280.556 us; speedup 1.0000x reference)
//
#include <hip/hip_runtime.h>
#include <math.h>

// Chamfer distance, N=2, D=3 fp32 — grid-pruned exact NN, wave-cooperative v2.
// r5 post-mortem: vol-gate dumped dense/wrap waves into per-lane path; sparse
// shell tail was serial dependent loads with 0.73 waves/SIMD. Fixes:
//  1) gate wave-uniform path on CANDIDATE COUNT (<=2048), counted wave-parallel;
//     row ranges broadcast via __shfl (loaded once in count phase).
//  2) unsatisfied lanes handled by WAVE-COOPERATIVE rectangular expansion
//     shells (one (z,y) row per lane, shfl-min reduce, uniform bound check).
//  3) pass2a+pass2b fused into one reduce_all dispatch.
// Exactness: scanned set always covers ball(q, margin-to-scanned-box); clamp
// is a projection (non-expansive) so domain-clamped faces are exhaustive.
// Determinism: slot->cellid map is deterministic (counting sort); candidate
// sets deterministic; fp min is order-independent; fixed-order reductions.

#define G 32
#define NC (G * G * G)
#define HLO -4.5f
#define HSPAN 9.0f
#define HCELL 0.28125f
#define QBLK 64
#define CAND_CAP 2048
#define P2A_BLOCKS 6
#define P2A_PAD 8

__device__ __forceinline__ int cell_coord(float x) {
    int i = (int)floorf((x - HLO) * ((float)G / HSPAN));
    return min(max(i, 0), G - 1);
}

__device__ __forceinline__ void scan_range(const float4* __restrict__ T,
                                           unsigned k, unsigned ke,
                                           float ax, float ay, float az,
                                           float& best) {
    for (; k + 2 <= ke; k += 2) {
        float4 b0 = T[k], b1 = T[k + 1];
        float d0 = fmaf(ax, b0.x, fmaf(ay, b0.y, fmaf(az, b0.z, b0.w)));
        float d1 = fmaf(ax, b1.x, fmaf(ay, b1.y, fmaf(az, b1.z, b1.w)));
        best = fminf(fminf(best, d0), d1);   // v_min3
    }
    if (k < ke) {
        float4 b = T[k];
        best = fminf(best, fmaf(ax, b.x, fmaf(ay, b.y, fmaf(az, b.z, b.w))));
    }
}

// ---------------- grid build / scan / scatter ----------------

__global__ __launch_bounds__(256) void grid_build(
    const float* __restrict__ c1, const float* __restrict__ c2,
    int P1, int P2, unsigned* __restrict__ hist,
    unsigned* __restrict__ cellid, unsigned* __restrict__ rank) {
    const int set = blockIdx.y;           // n*2 + cloud
    const int n = set >> 1, cl = set & 1;
    const int P = cl ? P2 : P1;
    const int i = blockIdx.x * 256 + threadIdx.x;
    if (i >= P) return;
    const float* p = (cl ? c2 + (size_t)n * P2 * 3 : c1 + (size_t)n * P1 * 3) + (size_t)i * 3;
    const int ix = cell_coord(p[0]), iy = cell_coord(p[1]), iz = cell_coord(p[2]);
    const unsigned c = ((unsigned)iz * G + iy) * G + ix;
    const unsigned r = atomicAdd(&hist[(size_t)set * NC + c], 1u);
    const int poff = n * (P1 + P2) + (cl ? P1 : 0);
    cellid[poff + i] = c;
    rank[poff + i] = r;
}

__global__ __launch_bounds__(1024) void grid_scan(
    const unsigned* __restrict__ hist, unsigned* __restrict__ starts) {
    const int set = blockIdx.x;
    const unsigned* h = hist + (size_t)set * NC;
    unsigned* st = starts + (size_t)set * (NC + 1);
    const int t = threadIdx.x;
    const int CH = NC / 1024;             // 32
    unsigned s = 0;
    for (int k = 0; k < CH; ++k) s += h[t * CH + k];
    __shared__ unsigned sd[1024];
    sd[t] = s;
    __syncthreads();
    for (int off = 1; off < 1024; off <<= 1) {
        unsigned v = (t >= off) ? sd[t - off] : 0u;
        __syncthreads();
        sd[t] += v;
        __syncthreads();
    }
    unsigned run = (t == 0) ? 0u : sd[t - 1];
    for (int k = 0; k < CH; ++k) {
        st[t * CH + k] = run;
        run += h[t * CH + k];
    }
    if (t == 1023) st[NC] = run;          // sentinel = total
}

__global__ __launch_bounds__(256) void grid_scatter(
    const float* __restrict__ c1, const float* __restrict__ c2,
    int P1, int P2, const unsigned* __restrict__ starts,
    const unsigned* __restrict__ cellid, const unsigned* __restrict__ rank,
    float4* __restrict__ sorted, unsigned* __restrict__ sidx) {
    const int set = blockIdx.y;
    const int n = set >> 1, cl = set & 1;
    const int P = cl ? P2 : P1;
    const int i = blockIdx.x * 256 + threadIdx.x;
    if (i >= P) return;
    const float* p = (cl ? c2 + (size_t)n * P2 * 3 : c1 + (size_t)n * P1 * 3) + (size_t)i * 3;
    const float x = p[0], y = p[1], z = p[2];
    const int poff = n * (P1 + P2) + (cl ? P1 : 0);
    const unsigned c = cellid[poff + i];
    const unsigned pos = starts[(size_t)set * (NC + 1) + c] + rank[poff + i];
    sorted[poff + pos] = make_float4(-2.f * x, -2.f * y, -2.f * z,
                                     fmaf(x, x, fmaf(y, y, z * z)));
    sidx[poff + pos] = i;
}

// ---------------- wave-cooperative query ----------------

__global__ __launch_bounds__(QBLK) void grid_query(
    int P1, int P2, const unsigned* __restrict__ starts,
    const float4* __restrict__ sorted, const unsigned* __restrict__ sidx,
    float* __restrict__ mk) {
    const int zz = blockIdx.y;            // n*2 + dir
    const int n = zz >> 1, dir = zz & 1;
    const int ts = n * 2 + (dir ? 0 : 1); // target set
    const int Pq = dir ? P2 : P1;
    const int qoff = n * (P1 + P2) + (dir ? P1 : 0);
    const int toff = n * (P1 + P2) + (dir ? 0 : P1);
    if (blockIdx.x * QBLK >= Pq) return;
    const unsigned* tst = starts + (size_t)ts * (NC + 1);
    const float4* T = sorted + toff;
    const int lane = threadIdx.x;

    int qi = blockIdx.x * QBLK + lane;
    const bool valid = qi < Pq;
    qi = min(qi, Pq - 1);

    const float4 q = sorted[qoff + qi];   // cell-sorted order
    const unsigned orig = sidx[qoff + qi];
    const float ax = -0.5f * q.x, ay = -0.5f * q.y, az = -0.5f * q.z, qw = q.w;
    const int cx = cell_coord(ax), cy = cell_coord(ay), cz = cell_coord(az);

    // wave-wide cell bounding box
    int bx0 = cx, bx1 = cx, by0 = cy, by1 = cy, bz0 = cz, bz1 = cz;
    #pragma unroll
    for (int o = 32; o; o >>= 1) {
        bx0 = min(bx0, __shfl_xor(bx0, o)); bx1 = max(bx1, __shfl_xor(bx1, o));
        by0 = min(by0, __shfl_xor(by0, o)); by1 = max(by1, __shfl_xor(by1, o));
        bz0 = min(bz0, __shfl_xor(bz0, o)); bz1 = max(bz1, __shfl_xor(bz1, o));
    }
    bx0 = max(bx0 - 1, 0); bx1 = min(bx1 + 1, G - 1);
    by0 = max(by0 - 1, 0); by1 = min(by1 + 1, G - 1);
    bz0 = max(bz0 - 1, 0); bz1 = min(bz1 + 1, G - 1);
    const int ys = by1 - by0 + 1;
    const int rows = ys * (bz1 - bz0 + 1);

    // count candidates wave-parallel; lane r holds row r's range (rows<=64 case)
    unsigned rs = 0, re = 0, cnt = 0;
    for (int r = lane; r < rows; r += 64) {
        const int zc = bz0 + r / ys, yc = by0 + r % ys;
        const int cbase = (zc * G + yc) * G;
        const unsigned a = tst[cbase + bx0], b = tst[cbase + bx1 + 1];
        if (r == lane) { rs = a; re = b; }
        cnt += b - a;
    }
    #pragma unroll
    for (int o = 32; o; o >>= 1) cnt += __shfl_xor(cnt, o);

    float best = INFINITY;
    int ex0, ex1, ey0, ey1, ez0, ez1;     // scanned (effective) box

    if (cnt <= CAND_CAP) {
        if (rows <= 64) {
            for (int r = 0; r < rows; ++r)
                scan_range(T, __shfl(rs, r), __shfl(re, r), ax, ay, az, best);
        } else {
            for (int zc = bz0; zc <= bz1; ++zc)
                for (int yc = by0; yc <= by1; ++yc) {
                    const int cbase = (zc * G + yc) * G;
                    scan_range(T, tst[cbase + bx0], tst[cbase + bx1 + 1],
                               ax, ay, az, best);
                }
        }
        ex0 = bx0; ex1 = bx1; ey0 = by0; ey1 = by1; ez0 = bz0; ez1 = bz1;
    } else {
        // per-lane own 3^3 (dense straddle waves)
        ex0 = max(cx - 1, 0); ex1 = min(cx + 1, G - 1);
        ey0 = max(cy - 1, 0); ey1 = min(cy + 1, G - 1);
        ez0 = max(cz - 1, 0); ez1 = min(cz + 1, G - 1);
        for (int zc = ez0; zc <= ez1; ++zc)
            for (int yc = ey0; yc <= ey1; ++yc) {
                const int cbase = (zc * G + yc) * G;
                scan_range(T, tst[cbase + ex0], tst[cbase + ex1 + 1],
                           ax, ay, az, best);
            }
    }

    // margin from q to scanned-box world boundary; clamped faces exhaustive.
    float mg = INFINITY;
    if (ex0 > 0)     mg = fminf(mg, ax - (HLO + (float)ex0 * HCELL));
    if (ex1 < G - 1) mg = fminf(mg, (HLO + (float)(ex1 + 1) * HCELL) - ax);
    if (ey0 > 0)     mg = fminf(mg, ay - (HLO + (float)ey0 * HCELL));
    if (ey1 < G - 1) mg = fminf(mg, (HLO + (float)(ey1 + 1) * HCELL) - ay);
    if (ez0 > 0)     mg = fminf(mg, az - (HLO + (float)ez0 * HCELL));
    if (ez1 < G - 1) mg = fminf(mg, (HLO + (float)(ez1 + 1) * HCELL) - az);

    float d2 = qw + best;

    // wave-cooperative rectangular expansion for unsatisfied lanes
    unsigned long long un = __ballot((!(d2 <= mg * mg)) && valid);
    while (un) {
        const int L = __ffsll((unsigned long long)un) - 1; un &= un - 1;
        const float qax = __shfl(ax, L), qay = __shfl(ay, L);
        const float qaz = __shfl(az, L), qqw = __shfl(qw, L);
        float qbest = __shfl(best, L);
        int px0 = __shfl(ex0, L), px1 = __shfl(ex1, L);
        int py0 = __shfl(ey0, L), py1 = __shfl(ey1, L);
        int pz0 = __shfl(ez0, L), pz1 = __shfl(ez1, L);
        for (int t = 0; t < G; ++t) {
            const int gx0 = max(px0 - 1, 0), gx1 = min(px1 + 1, G - 1);
            const int gy0 = max(py0 - 1, 0), gy1 = min(py1 + 1, G - 1);
            const int gz0 = max(pz0 - 1, 0), gz1 = min(pz1 + 1, G - 1);
            const int gys = gy1 - gy0 + 1;
            const int grows = gys * (gz1 - gz0 + 1);
            float lm = INFINITY;
            for (int r = lane; r < grows; r += 64) {
                const int zc = gz0 + r / gys, yc = gy0 + r % gys;
                const int cbase = (zc * G + yc) * G;
                if (zc < pz0 || zc > pz1 || yc < py0 || yc > py1) {
                    scan_range(T, tst[cbase + gx0], tst[cbase + gx1 + 1],
                               qax, qay, qaz, lm);
                } else {
                    if (gx0 < px0)
                        scan_range(T, tst[cbase + gx0], tst[cbase + px0],
                                   qax, qay, qaz, lm);
                    if (gx1 > px1)
                        scan_range(T, tst[cbase + px1 + 1], tst[cbase + gx1 + 1],
                                   qax, qay, qaz, lm);
                }
            }
            #pragma unroll
            for (int o = 32; o; o >>= 1) lm = fminf(lm, __shfl_xor(lm, o));
            qbest = fminf(qbest, lm);
            px0 = gx0; px1 = gx1; py0 = gy0; py1 = gy1; pz0 = gz0; pz1 = gz1;
            float qmg = INFINITY;
            if (px0 > 0)     qmg = fminf(qmg, qax - (HLO + (float)px0 * HCELL));
            if (px1 < G - 1) qmg = fminf(qmg, (HLO + (float)(px1 + 1) * HCELL) - qax);
            if (py0 > 0)     qmg = fminf(qmg, qay - (HLO + (float)py0 * HCELL));
            if (py1 < G - 1) qmg = fminf(qmg, (HLO + (float)(py1 + 1) * HCELL) - qay);
            if (pz0 > 0)     qmg = fminf(qmg, qaz - (HLO + (float)pz0 * HCELL));
            if (pz1 < G - 1) qmg = fminf(qmg, (HLO + (float)(pz1 + 1) * HCELL) - qaz);
            if (qqw + qbest <= qmg * qmg) break;
        }
        if (lane == L) d2 = qqw + qbest;
    }
    if (valid) mk[qoff + orig] = d2;
}

// ---------------- fused final reduction (deterministic fixed order) ----------

__global__ __launch_bounds__(1024) void reduce_all(
    const float* __restrict__ mk, int P1, int P2, float* __restrict__ out) {
    const int t = threadIdx.x;
    const int off[4] = {0, P1, P1 + P2, P1 + P2 + P1};
    const int len[4] = {P1, P2, P1, P2};
    float acc[4];
    #pragma unroll
    for (int z = 0; z < 4; ++z) {
        float s = 0.f;
        const float* p = mk + off[z];
        for (int i = t; i < len[z]; i += 1024) s += p[i];
        acc[z] = s;
    }
    __shared__ float red[1024];
    float res[4];
    for (int z = 0; z < 4; ++z) {
        red[t] = acc[z];
        __syncthreads();
        for (int o = 512; o > 0; o >>= 1) {
            if (t < o) red[t] += red[t + o];
            __syncthreads();
        }
        res[z] = red[0];
        __syncthreads();
    }
    if (t == 0) {
        out[0] = res[0] / (float)P1 + res[1] / (float)P2;
        out[1] = res[2] / (float)P1 + res[3] / (float)P2;
    }
}

// ---------------- fallback brute-force path (r2 config) ----------------

#define BLOCK 256
#define QPT 4
#define SEG 384

__device__ __forceinline__ unsigned fkey(float f) {
    unsigned u = __float_as_uint(f);
    unsigned mask = (unsigned)((int)u >> 31) | 0x80000000u;
    return u ^ mask;
}
__device__ __forceinline__ float fdec(unsigned k) {
    unsigned mask = (k & 0x80000000u) ? 0x80000000u : 0xFFFFFFFFu;
    return __uint_as_float(k ^ mask);
}

__global__ __launch_bounds__(BLOCK) void chamfer_pass1(
    const float* __restrict__ c1, const float* __restrict__ c2,
    int P1, int P2, unsigned* __restrict__ mk_all) {
    const int z = blockIdx.z;
    const int n = z >> 1, dir = z & 1;
    const int Pq = dir ? P2 : P1;
    const int Pt = dir ? P1 : P2;
    const float* Q = (dir ? c2 : c1) + (size_t)n * Pq * 3;
    const float* T = (dir ? c1 : c2) + (size_t)n * Pt * 3;
    unsigned* mk = mk_all + (size_t)n * (P1 + P2) + (dir ? P1 : 0);

    __shared__ float4 tile[SEG];
    const int t0 = blockIdx.y * SEG;
    const int nt = Pt - t0;
    for (int j = threadIdx.x; j < SEG; j += BLOCK) {
        float4 v;
        if (j < nt) {
            const float* p = T + (size_t)(t0 + j) * 3;
            float x = p[0], y = p[1], w = p[2];
            v = make_float4(-2.f * x, -2.f * y, -2.f * w,
                            fmaf(x, x, fmaf(y, y, w * w)));
        } else {
            v = make_float4(0.f, 0.f, 0.f, INFINITY);
        }
        tile[j] = v;
    }
    __syncthreads();

    const int qbase = blockIdx.x * (BLOCK * QPT) + threadIdx.x;
    float ax[QPT], ay[QPT], az[QPT], sq[QPT], m[QPT];
    #pragma unroll
    for (int k = 0; k < QPT; ++k) {
        const int qi = qbase + k * BLOCK;
        ax[k] = 0.f; ay[k] = 0.f; az[k] = 0.f;
        if (qi < Pq) {
            const float* p = Q + (size_t)qi * 3;
            ax[k] = p[0]; ay[k] = p[1]; az[k] = p[2];
        }
        sq[k] = fmaf(ax[k], ax[k], fmaf(ay[k], ay[k], az[k] * az[k]));
        m[k] = INFINITY;
    }
    #pragma unroll 4
    for (int j = 0; j < SEG; j += 2) {
        float4 b0 = tile[j];
        float4 b1 = tile[j + 1];
        #pragma unroll
        for (int k = 0; k < QPT; ++k) {
            float d0 = fmaf(ax[k], b0.x, fmaf(ay[k], b0.y, fmaf(az[k], b0.z, b0.w)));
            float d1 = fmaf(ax[k], b1.x, fmaf(ay[k], b1.y, fmaf(az[k], b1.z, b1.w)));
            m[k] = fminf(fminf(m[k], d0), d1);
        }
    }
    #pragma unroll
    for (int k = 0; k < QPT; ++k) {
        const int qi = qbase + k * BLOCK;
        if (qi < Pq) atomicMin(&mk[qi], fkey(sq[k] + m[k]));
    }
}

__global__ __launch_bounds__(256) void pass2a_key(
    const unsigned* __restrict__ mk_all, int P1, int P2,
    float* __restrict__ partial) {
    const int z = blockIdx.y;
    const int b = blockIdx.x;
    const int n = z >> 1, dir = z & 1;
    const int Pq = dir ? P2 : P1;
    const unsigned* mk = mk_all + (size_t)n * (P1 + P2) + (dir ? P1 : 0);
    const int span = (Pq + P2A_BLOCKS - 1) / P2A_BLOCKS;
    const int lo = b * span;
    const int hi = min(lo + span, Pq);
    float s = 0.f;
    for (int q = lo + threadIdx.x; q < hi; q += 256) s += fdec(mk[q]);
    __shared__ float red[256];
    red[threadIdx.x] = s;
    __syncthreads();
    for (int off = 128; off > 0; off >>= 1) {
        if (threadIdx.x < off) red[threadIdx.x] += red[threadIdx.x + off];
        __syncthreads();
    }
    if (threadIdx.x == 0) partial[z * P2A_PAD + b] = red[0];
}

__global__ void pass2b(const float* __restrict__ partial,
                       int P1, int P2, float* __restrict__ out) {
    int n = threadIdx.x;
    if (n < 2) {
        float sA = 0.f, sB = 0.f;
        for (int b = 0; b < P2A_BLOCKS; ++b) {
            sA += partial[(n * 2 + 0) * P2A_PAD + b];
            sB += partial[(n * 2 + 1) * P2A_PAD + b];
        }
        out[n] = sA / (float)P1 + sB / (float)P2;
    }
}

// ---------------- launch ----------------

static inline size_t al256(size_t x) { return (x + 255) & ~(size_t)255; }

extern "C" void kernel_launch(void* const* d_in, const int* in_sizes, int n_in,
                              void* d_out, int out_size, void* d_ws, size_t ws_size,
                              hipStream_t stream) {
    const float* c1 = (const float*)d_in[0];
    const float* c2 = (const float*)d_in[1];
    const int N = 2;
    const int P1 = in_sizes[0] / (N * 3);
    const int P2 = in_sizes[1] / (N * 3);
    const int TP = N * (P1 + P2);
    const int Pmax = P1 > P2 ? P1 : P2;

    // ws layout (256-aligned)
    size_t o_hist = 0;
    size_t o_starts = al256(o_hist + (size_t)4 * NC * 4);
    size_t o_cellid = al256(o_starts + (size_t)4 * (NC + 1) * 4);
    size_t o_rank = al256(o_cellid + (size_t)TP * 4);
    size_t o_sidx = al256(o_rank + (size_t)TP * 4);
    size_t o_mk = al256(o_sidx + (size_t)TP * 4);
    size_t o_part = al256(o_mk + (size_t)TP * 4);
    size_t o_sorted = al256(o_part + (size_t)4 * P2A_PAD * 4);
    size_t need = o_sorted + (size_t)TP * 16;

    char* ws = (char*)d_ws;
    float* partial = (float*)(ws + o_part);

    if (ws_size >= need) {
        unsigned* hist = (unsigned*)(ws + o_hist);
        unsigned* starts = (unsigned*)(ws + o_starts);
        unsigned* cellid = (unsigned*)(ws + o_cellid);
        unsigned* rank = (unsigned*)(ws + o_rank);
        unsigned* sidx = (unsigned*)(ws + o_sidx);
        float* mk = (float*)(ws + o_mk);
        float4* sorted = (float4*)(ws + o_sorted);

        hipMemsetAsync(hist, 0, (size_t)4 * NC * 4, stream);

        dim3 gb((Pmax + 255) / 256, 4);
        grid_build<<<gb, 256, 0, stream>>>(c1, c2, P1, P2, hist, cellid, rank);
        grid_scan<<<4, 1024, 0, stream>>>(hist, starts);
        grid_scatter<<<gb, 256, 0, stream>>>(c1, c2, P1, P2, starts, cellid, rank,
                                             sorted, sidx);
        dim3 gq((Pmax + QBLK - 1) / QBLK, 4);
        grid_query<<<gq, QBLK, 0, stream>>>(P1, P2, starts, sorted, sidx, mk);

        reduce_all<<<1, 1024, 0, stream>>>(mk, P1, P2, (float*)d_out);
    } else {
        // fallback: brute force (r2 config)
        unsigned* mk = (unsigned*)(ws + o_mk);
        hipMemsetAsync(mk, 0xFF, (size_t)TP * 4, stream);
        dim3 g1((Pmax + BLOCK * QPT - 1) / (BLOCK * QPT),
                (Pmax + SEG - 1) / SEG, 2 * N);
        chamfer_pass1<<<g1, BLOCK, 0, stream>>>(c1, c2, P1, P2, mk);
        dim3 g2(P2A_BLOCKS, 4);
        pass2a_key<<<g2, 256, 0, stream>>>(mk, P1, P2, partial);
        pass2b<<<1, 64, 0, stream>>>(partial, P1, P2, (float*)d_out);
    }
}